// Round 10
// baseline (157.034 us; speedup 1.0000x reference)
//
#include <hip/hip_runtime.h>

#define MARGIN 0.3f

typedef __attribute__((ext_vector_type(8))) short short8;
typedef __attribute__((ext_vector_type(4))) float floatx4;

#define AS_GLOBAL(p) ((const __attribute__((address_space(1))) char*)(p))
#define AS_LDS(p)    ((__attribute__((address_space(3))) char*)(p))

// ---- helpers ----------------------------------------------------------------

// order-preserving float->uint encoding so unsigned atomicMin == float min
__device__ __forceinline__ unsigned enc_f32(float f) {
    unsigned u = __float_as_uint(f);
    return (u & 0x80000000u) ? ~u : (u | 0x80000000u);
}
__device__ __forceinline__ float dec_f32(unsigned u) {
    return (u & 0x80000000u) ? __uint_as_float(u & 0x7fffffffu)
                             : __uint_as_float(~u);
}
// fp32 -> bf16 bits, round-to-nearest-even
__device__ __forceinline__ short f2bf(float f) {
    unsigned u = __float_as_uint(f);
    u = u + 0x7fffu + ((u >> 16) & 1u);
    return (short)(u >> 16);
}

// Fragment-native global layout: element (row, k) with g16=row/16, r=row%16,
// kk=k/32, q=(k%32)/8, e=k%8 lives at  g16*2048 + kk*512 + q*128 + r*8 + e.
// One wave fragment load = base + lane*8 shorts = 64 lanes x 16 B contiguous.

// ---- kernel 1: prepass (fully coalesced via LDS transpose) ------------------
// 512 blocks x 256 thr; block b owns rows [b*16, b*16+16) = one g16 group.
// Read coalesced fp32 -> convert -> LDS (padded, 2-way banks) -> write the
// 4 KB fragment-native block contiguously (R7-prep wrote 16B/256B-stride,
// ~4x write inflation). Also exact fp32 sq1/sq2/posd + inits.
__global__ __launch_bounds__(256)
void prep_kernel(const float* __restrict__ z1, const float* __restrict__ z2,
                 short* __restrict__ z1b, short* __restrict__ z2b,
                 float* __restrict__ sq1, float* __restrict__ sq2,
                 float* __restrict__ posd, unsigned* __restrict__ rowmin,
                 unsigned* __restrict__ cnt, float* __restrict__ out) {
    __shared__ short l1[16 * 136], l2[16 * 136];    // 136 = 17*8: +1 part pad
    const int tid = threadIdx.x, b = blockIdx.x;
    const int r16 = tid >> 4, p = tid & 15;         // row-in-group, part
    const int row = b * 16 + r16;
    const int f0  = row * 32 + p * 2;               // 2 consecutive float4
    float4 fa0 = ((const float4*)z1)[f0], fa1 = ((const float4*)z1)[f0 + 1];
    float4 fb0 = ((const float4*)z2)[f0], fb1 = ((const float4*)z2)[f0 + 1];
    short8 sa = { f2bf(fa0.x), f2bf(fa0.y), f2bf(fa0.z), f2bf(fa0.w),
                  f2bf(fa1.x), f2bf(fa1.y), f2bf(fa1.z), f2bf(fa1.w) };
    short8 sb = { f2bf(fb0.x), f2bf(fb0.y), f2bf(fb0.z), f2bf(fb0.w),
                  f2bf(fb1.x), f2bf(fb1.y), f2bf(fb1.z), f2bf(fb1.w) };
    *(short8*)&l1[r16 * 136 + p * 8] = sa;
    *(short8*)&l2[r16 * 136 + p * 8] = sb;

    float s1 = fa0.x*fa0.x + fa0.y*fa0.y + fa0.z*fa0.z + fa0.w*fa0.w
             + fa1.x*fa1.x + fa1.y*fa1.y + fa1.z*fa1.z + fa1.w*fa1.w;
    float s2 = fb0.x*fb0.x + fb0.y*fb0.y + fb0.z*fb0.z + fb0.w*fb0.w
             + fb1.x*fb1.x + fb1.y*fb1.y + fb1.z*fb1.z + fb1.w*fb1.w;
    float dx0 = fa0.x-fb0.x, dy0 = fa0.y-fb0.y, dz0 = fa0.z-fb0.z, dw0 = fa0.w-fb0.w;
    float dx1 = fa1.x-fb1.x, dy1 = fa1.y-fb1.y, dz1 = fa1.z-fb1.z, dw1 = fa1.w-fb1.w;
    float p2 = dx0*dx0 + dy0*dy0 + dz0*dz0 + dw0*dw0
             + dx1*dx1 + dy1*dy1 + dz1*dz1 + dw1*dw1;
    #pragma unroll
    for (int m = 8; m >= 1; m >>= 1) {              // reduce over 16 parts
        s1 += __shfl_xor(s1, m);
        s2 += __shfl_xor(s2, m);
        p2 += __shfl_xor(p2, m);
    }
    if (p == 0) { sq1[row] = s1; sq2[row] = s2; posd[row] = sqrtf(p2); }

    __syncthreads();
    {   // out short8 #tid of this g16 block: r=tid&15, q=(tid>>4)&3, kk=(tid>>6)&3
        int r = tid & 15, psrc = ((tid >> 6) & 3) * 4 + ((tid >> 4) & 3);
        short8 va = *(const short8*)&l1[r * 136 + psrc * 8];
        short8 vb = *(const short8*)&l2[r * 136 + psrc * 8];
        *(short8*)&z1b[(size_t)b * 2048 + tid * 8] = va;   // 4 KB contiguous
        *(short8*)&z2b[(size_t)b * 2048 + tid * 8] = vb;
    }
    if (tid < 16) rowmin[b * 16 + tid] = 0xFFFFFFFFu;
    if (b == 0) {
        if (tid < 16) cnt[tid] = 0u;
        if (tid == 0) out[0] = 0.0f;
    }
}

// ---- kernel 2: B-panel-in-LDS GEMM + row-min + fused loss -------------------
// grid (32 panels, 16 rowgroups) = 512 blocks = 2/CU, one round.
// Block stages its 256-col B panel (64 KB, fragment-native) into LDS ONCE via
// global_load_lds; single __syncthreads. Waves then stream 128 rows each:
// 4 outer iters x (8 coalesced A-frag loads; 16 col-tiles x [4 ds_read_b128 +
// 8 MFMA + reg fold]). B never occupies persistent registers (the R7/R8/R9
// failure mode); A frags live only one outer iter.
__global__ __launch_bounds__(256, 2)
void gemm_min_kernel(const short* __restrict__ z1b, const short* __restrict__ z2b,
                     const float* __restrict__ sq1, const float* __restrict__ sq2,
                     const float* __restrict__ posd,
                     unsigned* __restrict__ rowmin, unsigned* __restrict__ cnt,
                     float* __restrict__ out, int n)
{
    __shared__ short Bs[32768];                     // 64 KB B panel
    __shared__ float lsum[4];
    __shared__ int   fin_s;

    const int panel = blockIdx.x;                   // 256 cols
    const int rg    = blockIdx.y;                   // 512 rows
    const int tid = threadIdx.x, w = tid >> 6, lane = tid & 63;
    const int quad = lane >> 4, l15 = lane & 15;
    const int colp = panel * 256;

    const short* gB = z2b + (size_t)panel * 32768;
    #pragma unroll
    for (int it = 0; it < 16; ++it) {               // flat 64 KB DMA copy
        int off = it * 2048 + tid * 8;
        __builtin_amdgcn_global_load_lds(AS_GLOBAL(gB + off), AS_LDS(Bs + off), 16, 0, 0);
    }
    __syncthreads();                                // only barrier in the kernel

    #pragma unroll 1                                // MUST NOT unroll (reg pressure)
    for (int o = 0; o < 4; ++o) {
        const int rA = rg * 512 + w * 128 + o * 32; // two 16-row tiles
        const short* pa = z1b + (size_t)(rA >> 4) * 2048 + lane * 8;
        short8 af0[4], af1[4];
        #pragma unroll
        for (int kk = 0; kk < 4; ++kk) {
            af0[kk] = *(const short8*)(pa + kk * 512);          // rows rA..+16
            af1[kk] = *(const short8*)(pa + 2048 + kk * 512);   // rows rA+16..+32
        }
        float vmin0[4], vmin1[4];
        #pragma unroll
        for (int reg = 0; reg < 4; ++reg) { vmin0[reg] = 3.0e38f; vmin1[reg] = 3.0e38f; }

        #pragma unroll
        for (int ct = 0; ct < 16; ++ct) {
            short8 bf[4];
            #pragma unroll
            for (int kk = 0; kk < 4; ++kk)
                bf[kk] = *(const short8*)&Bs[ct * 2048 + kk * 512 + lane * 8];
            floatx4 a0 = (floatx4)0.0f, a1 = (floatx4)0.0f;
            #pragma unroll
            for (int kk = 0; kk < 4; ++kk) {
                a0 = __builtin_amdgcn_mfma_f32_16x16x32_bf16(af0[kk], bf[kk], a0, 0, 0, 0);
                a1 = __builtin_amdgcn_mfma_f32_16x16x32_bf16(af1[kk], bf[kk], a1, 0, 0, 0);
            }
            const int colb = colp + ct * 16;
            const float s2v = sq2[colb + l15];      // 64 B, L1-resident
            const bool d0 = (colb == rA);           // wave-uniform diag flags
            const bool d1 = (colb == rA + 16);
            #pragma unroll
            for (int reg = 0; reg < 4; ++reg) {     // C/D: col=l15, row=quad*4+reg
                bool eq = (quad * 4 + reg) == l15;
                float v0 = fmaf(-2.0f, a0[reg], s2v);
                float v1 = fmaf(-2.0f, a1[reg], s2v);
                v0 = (d0 && eq) ? 3.0e38f : v0;
                v1 = (d1 && eq) ? 3.0e38f : v1;
                vmin0[reg] = fminf(vmin0[reg], v0);
                vmin1[reg] = fminf(vmin1[reg], v1);
            }
        }
        // min over each quad's 16 lanes; one atomicMin per row
        #pragma unroll
        for (int reg = 0; reg < 4; ++reg) {
            float v0 = vmin0[reg], v1 = vmin1[reg];
            #pragma unroll
            for (int m = 8; m >= 1; m >>= 1) {
                v0 = fminf(v0, __shfl_xor(v0, m));
                v1 = fminf(v1, __shfl_xor(v1, m));
            }
            if (l15 == 0) {
                atomicMin(&rowmin[rA + quad * 4 + reg],      enc_f32(v0));
                atomicMin(&rowmin[rA + 16 + quad * 4 + reg], enc_f32(v1));
            }
        }
    }

    __syncthreads();
    if (tid == 0) {
        __threadfence();    // release: this block's mins visible before bump
        fin_s = (atomicAdd(&cnt[rg], 1u) == 31u);
    }
    __syncthreads();
    if (!fin_s) return;
    __threadfence();        // acquire: see all 32 panels' mins

    // fused loss for rows [rg*512, rg*512+512): thread = two rows
    float acc = 0.0f;
    #pragma unroll
    for (int k = 0; k < 2; ++k) {
        int i = rg * 512 + k * 256 + tid;
        unsigned rm = atomicMin(&rowmin[i], 0xFFFFFFFFu);    // coherent forced read
        float hard = sqrtf(fmaxf(sq1[i] + dec_f32(rm), 0.0f));
        acc += fmaxf(posd[i] - hard + MARGIN, 0.0f);
    }
    #pragma unroll
    for (int m = 32; m >= 1; m >>= 1) acc += __shfl_xor(acc, m);
    if (lane == 0) lsum[w] = acc;
    __syncthreads();
    if (tid == 0)
        atomicAdd(out, (lsum[0] + lsum[1] + lsum[2] + lsum[3]) / (float)n);
}

// ---- launch -----------------------------------------------------------------
extern "C" void kernel_launch(void* const* d_in, const int* in_sizes, int n_in,
                              void* d_out, int out_size, void* d_ws, size_t ws_size,
                              hipStream_t stream) {
    const float* z1 = (const float*)d_in[0];
    const float* z2 = (const float*)d_in[1];
    const int n = in_sizes[0] / 128;            // 8192

    char* ws = (char*)d_ws;
    short*    z1b    = (short*)ws;                                     // 2 MB
    short*    z2b    = (short*)(ws + (size_t)n * 128 * 2);             // 2 MB
    float*    sq1    = (float*)(ws + (size_t)n * 128 * 4);             // 32 KB
    float*    sq2    = (float*)(ws + (size_t)n * 128 * 4 + n * 4);     // 32 KB
    float*    posd   = (float*)(ws + (size_t)n * 128 * 4 + n * 8);     // 32 KB
    unsigned* rowmin = (unsigned*)(ws + (size_t)n * 128 * 4 + n * 12); // 32 KB
    unsigned* cnt    = (unsigned*)(ws + (size_t)n * 128 * 4 + n * 16); // 64 B
    float*    out    = (float*)d_out;

    prep_kernel<<<n / 16, 256, 0, stream>>>(z1, z2, z1b, z2b, sq1, sq2, posd,
                                            rowmin, cnt, out);
    dim3 grid(32, n / 512);                     // (col panels, row groups)
    gemm_min_kernel<<<grid, 256, 0, stream>>>(z1b, z2b, sq1, sq2, posd,
                                              rowmin, cnt, out, n);
}

// Round 11
// 108.941 us; speedup vs baseline: 1.4415x; 1.4415x over previous
//
#include <hip/hip_runtime.h>

#define MARGIN 0.3f

typedef __attribute__((ext_vector_type(8))) short short8;
typedef __attribute__((ext_vector_type(4))) float floatx4;

#define AS_GLOBAL(p) ((const __attribute__((address_space(1))) char*)(p))
#define AS_LDS(p)    ((__attribute__((address_space(3))) char*)(p))

// ---- helpers ----------------------------------------------------------------

// order-preserving float->uint encoding so unsigned atomicMin == float min
__device__ __forceinline__ unsigned enc_f32(float f) {
    unsigned u = __float_as_uint(f);
    return (u & 0x80000000u) ? ~u : (u | 0x80000000u);
}
__device__ __forceinline__ float dec_f32(unsigned u) {
    return (u & 0x80000000u) ? __uint_as_float(u & 0x7fffffffu)
                             : __uint_as_float(~u);
}
// fp32 -> bf16 bits, round-to-nearest-even
__device__ __forceinline__ short f2bf(float f) {
    unsigned u = __float_as_uint(f);
    u = u + 0x7fffu + ((u >> 16) & 1u);
    return (short)(u >> 16);
}

// Fragment-native global layout: element (row, k) with g16=row/16, r=row%16,
// kk=k/32, q=(k%32)/8, e=k%8 lives at  g16*2048 + kk*512 + q*128 + r*8 + e.
// One wave fragment load = base + lane*8 shorts = 64 lanes x 16 B contiguous.

// ---- kernel 1: prepass (coalesced via LDS transpose; verified R10) ----------
__global__ __launch_bounds__(256)
void prep_kernel(const float* __restrict__ z1, const float* __restrict__ z2,
                 short* __restrict__ z1b, short* __restrict__ z2b,
                 float* __restrict__ sq1, float* __restrict__ sq2,
                 float* __restrict__ posd, unsigned* __restrict__ rowmin,
                 unsigned* __restrict__ cnt, float* __restrict__ out) {
    __shared__ short l1[16 * 136], l2[16 * 136];    // 136 = 17*8: pad
    const int tid = threadIdx.x, b = blockIdx.x;
    const int r16 = tid >> 4, p = tid & 15;         // row-in-group, part
    const int row = b * 16 + r16;
    const int f0  = row * 32 + p * 2;               // 2 consecutive float4
    float4 fa0 = ((const float4*)z1)[f0], fa1 = ((const float4*)z1)[f0 + 1];
    float4 fb0 = ((const float4*)z2)[f0], fb1 = ((const float4*)z2)[f0 + 1];
    short8 sa = { f2bf(fa0.x), f2bf(fa0.y), f2bf(fa0.z), f2bf(fa0.w),
                  f2bf(fa1.x), f2bf(fa1.y), f2bf(fa1.z), f2bf(fa1.w) };
    short8 sb = { f2bf(fb0.x), f2bf(fb0.y), f2bf(fb0.z), f2bf(fb0.w),
                  f2bf(fb1.x), f2bf(fb1.y), f2bf(fb1.z), f2bf(fb1.w) };
    *(short8*)&l1[r16 * 136 + p * 8] = sa;
    *(short8*)&l2[r16 * 136 + p * 8] = sb;

    float s1 = fa0.x*fa0.x + fa0.y*fa0.y + fa0.z*fa0.z + fa0.w*fa0.w
             + fa1.x*fa1.x + fa1.y*fa1.y + fa1.z*fa1.z + fa1.w*fa1.w;
    float s2 = fb0.x*fb0.x + fb0.y*fb0.y + fb0.z*fb0.z + fb0.w*fb0.w
             + fb1.x*fb1.x + fb1.y*fb1.y + fb1.z*fb1.z + fb1.w*fb1.w;
    float dx0 = fa0.x-fb0.x, dy0 = fa0.y-fb0.y, dz0 = fa0.z-fb0.z, dw0 = fa0.w-fb0.w;
    float dx1 = fa1.x-fb1.x, dy1 = fa1.y-fb1.y, dz1 = fa1.z-fb1.z, dw1 = fa1.w-fb1.w;
    float p2 = dx0*dx0 + dy0*dy0 + dz0*dz0 + dw0*dw0
             + dx1*dx1 + dy1*dy1 + dz1*dz1 + dw1*dw1;
    #pragma unroll
    for (int m = 8; m >= 1; m >>= 1) {              // reduce over 16 parts
        s1 += __shfl_xor(s1, m);
        s2 += __shfl_xor(s2, m);
        p2 += __shfl_xor(p2, m);
    }
    if (p == 0) { sq1[row] = s1; sq2[row] = s2; posd[row] = sqrtf(p2); }

    __syncthreads();
    {   // out short8 #tid of this g16 block: r=tid&15, q=(tid>>4)&3, kk=(tid>>6)&3
        int r = tid & 15, psrc = ((tid >> 6) & 3) * 4 + ((tid >> 4) & 3);
        short8 va = *(const short8*)&l1[r * 136 + psrc * 8];
        short8 vb = *(const short8*)&l2[r * 136 + psrc * 8];
        *(short8*)&z1b[(size_t)b * 2048 + tid * 8] = va;   // 4 KB contiguous
        *(short8*)&z2b[(size_t)b * 2048 + tid * 8] = vb;
    }
    if (tid < 16) rowmin[b * 16 + tid] = 0xFFFFFFFFu;
    if (b == 0) {
        if (tid < 16) cnt[tid] = 0u;
        if (tid == 0) out[0] = 0.0f;
    }
}

// ---- kernel 2: 128-col B panel in LDS + streamed A rows + fused loss --------
// grid (64 panels of 128 cols, 16 rowgroups of 512 rows) = 1024 blocks =
// 4/CU (LDS 32 KB). Panel staged ONCE via global_load_lds, single barrier.
// Waves stream 128 rows each: 4 o-iters x (8 A-frag loads; 8 col-tiles x
// [4 ds_read_b128 + 8 MFMA + fold]). #pragma unroll 1 on BOTH loops: R10's
// unrolled ct-loop hoisted 64 ds_reads (256 regs) -> 290 MB scratch traffic.
__global__ __launch_bounds__(256, 2)
void gemm_min_kernel(const short* __restrict__ z1b, const short* __restrict__ z2b,
                     const float* __restrict__ sq1, const float* __restrict__ sq2,
                     const float* __restrict__ posd,
                     unsigned* __restrict__ rowmin, unsigned* __restrict__ cnt,
                     float* __restrict__ out, int n)
{
    __shared__ short Bs[16384];                     // 32 KB B panel (128 cols)
    __shared__ float lsum[4];
    __shared__ int   fin_s;

    const int panel = blockIdx.x;                   // 128 cols
    const int rg    = blockIdx.y;                   // 512 rows
    const int tid = threadIdx.x, w = tid >> 6, lane = tid & 63;
    const int quad = lane >> 4, l15 = lane & 15;
    const int colp = panel * 128;

    const short* gB = z2b + (size_t)panel * 16384;
    #pragma unroll
    for (int it = 0; it < 8; ++it) {                // flat 32 KB DMA copy
        int off = it * 2048 + tid * 8;
        __builtin_amdgcn_global_load_lds(AS_GLOBAL(gB + off), AS_LDS(Bs + off), 16, 0, 0);
    }
    __syncthreads();                                // only barrier in the kernel

    #pragma unroll 1
    for (int o = 0; o < 4; ++o) {
        const int rA = rg * 512 + w * 128 + o * 32; // two 16-row tiles
        const short* pa = z1b + (size_t)(rA >> 4) * 2048 + lane * 8;
        short8 af0[4], af1[4];
        #pragma unroll
        for (int kk = 0; kk < 4; ++kk) {
            af0[kk] = *(const short8*)(pa + kk * 512);          // rows rA..+16
            af1[kk] = *(const short8*)(pa + 2048 + kk * 512);   // rows rA+16..+32
        }
        float vmin0[4], vmin1[4];
        #pragma unroll
        for (int reg = 0; reg < 4; ++reg) { vmin0[reg] = 3.0e38f; vmin1[reg] = 3.0e38f; }

        #pragma unroll 1                            // DO NOT unroll (reg pressure)
        for (int ct = 0; ct < 8; ++ct) {
            short8 bf[4];
            #pragma unroll
            for (int kk = 0; kk < 4; ++kk)
                bf[kk] = *(const short8*)&Bs[ct * 2048 + kk * 512 + lane * 8];
            floatx4 a0 = (floatx4)0.0f, a1 = (floatx4)0.0f;
            #pragma unroll
            for (int kk = 0; kk < 4; ++kk) {
                a0 = __builtin_amdgcn_mfma_f32_16x16x32_bf16(af0[kk], bf[kk], a0, 0, 0, 0);
                a1 = __builtin_amdgcn_mfma_f32_16x16x32_bf16(af1[kk], bf[kk], a1, 0, 0, 0);
            }
            const int colb = colp + ct * 16;
            const float s2v = sq2[colb + l15];      // 64 B line, L1-resident
            const bool d0 = (colb == rA);           // wave-uniform diag flags
            const bool d1 = (colb == rA + 16);
            #pragma unroll
            for (int reg = 0; reg < 4; ++reg) {     // C/D: col=l15, row=quad*4+reg
                bool eq = (quad * 4 + reg) == l15;
                float v0 = fmaf(-2.0f, a0[reg], s2v);
                float v1 = fmaf(-2.0f, a1[reg], s2v);
                v0 = (d0 && eq) ? 3.0e38f : v0;
                v1 = (d1 && eq) ? 3.0e38f : v1;
                vmin0[reg] = fminf(vmin0[reg], v0);
                vmin1[reg] = fminf(vmin1[reg], v1);
            }
        }
        // min over each quad's 16 lanes; one atomicMin per row
        #pragma unroll
        for (int reg = 0; reg < 4; ++reg) {
            float v0 = vmin0[reg], v1 = vmin1[reg];
            #pragma unroll
            for (int m = 8; m >= 1; m >>= 1) {
                v0 = fminf(v0, __shfl_xor(v0, m));
                v1 = fminf(v1, __shfl_xor(v1, m));
            }
            if (l15 == 0) {
                atomicMin(&rowmin[rA + quad * 4 + reg],      enc_f32(v0));
                atomicMin(&rowmin[rA + 16 + quad * 4 + reg], enc_f32(v1));
            }
        }
    }

    __syncthreads();
    if (tid == 0) {
        __threadfence();    // release: this block's mins visible before bump
        fin_s = (atomicAdd(&cnt[rg], 1u) == 63u);
    }
    __syncthreads();
    if (!fin_s) return;
    __threadfence();        // acquire: see all 64 panels' mins

    // fused loss for rows [rg*512, rg*512+512): thread = two rows
    float acc = 0.0f;
    #pragma unroll
    for (int k = 0; k < 2; ++k) {
        int i = rg * 512 + k * 256 + tid;
        unsigned rm = atomicMin(&rowmin[i], 0xFFFFFFFFu);    // coherent forced read
        float hard = sqrtf(fmaxf(sq1[i] + dec_f32(rm), 0.0f));
        acc += fmaxf(posd[i] - hard + MARGIN, 0.0f);
    }
    #pragma unroll
    for (int m = 32; m >= 1; m >>= 1) acc += __shfl_xor(acc, m);
    if (lane == 0) lsum[w] = acc;
    __syncthreads();
    if (tid == 0)
        atomicAdd(out, (lsum[0] + lsum[1] + lsum[2] + lsum[3]) / (float)n);
}

// ---- launch -----------------------------------------------------------------
extern "C" void kernel_launch(void* const* d_in, const int* in_sizes, int n_in,
                              void* d_out, int out_size, void* d_ws, size_t ws_size,
                              hipStream_t stream) {
    const float* z1 = (const float*)d_in[0];
    const float* z2 = (const float*)d_in[1];
    const int n = in_sizes[0] / 128;            // 8192

    char* ws = (char*)d_ws;
    short*    z1b    = (short*)ws;                                     // 2 MB
    short*    z2b    = (short*)(ws + (size_t)n * 128 * 2);             // 2 MB
    float*    sq1    = (float*)(ws + (size_t)n * 128 * 4);             // 32 KB
    float*    sq2    = (float*)(ws + (size_t)n * 128 * 4 + n * 4);     // 32 KB
    float*    posd   = (float*)(ws + (size_t)n * 128 * 4 + n * 8);     // 32 KB
    unsigned* rowmin = (unsigned*)(ws + (size_t)n * 128 * 4 + n * 12); // 32 KB
    unsigned* cnt    = (unsigned*)(ws + (size_t)n * 128 * 4 + n * 16); // 64 B
    float*    out    = (float*)d_out;

    prep_kernel<<<n / 16, 256, 0, stream>>>(z1, z2, z1b, z2b, sq1, sq2, posd,
                                            rowmin, cnt, out);
    dim3 grid(64, n / 512);                     // (col panels, row groups)
    gemm_min_kernel<<<grid, 256, 0, stream>>>(z1b, z2b, sq1, sq2, posd,
                                              rowmin, cnt, out, n);
}

// Round 12
// 103.260 us; speedup vs baseline: 1.5208x; 1.0550x over previous
//
#include <hip/hip_runtime.h>

#define MARGIN 0.3f

typedef __attribute__((ext_vector_type(8))) short short8;
typedef __attribute__((ext_vector_type(4))) float floatx4;

#define AS_GLOBAL(p) ((const __attribute__((address_space(1))) char*)(p))
#define AS_LDS(p)    ((__attribute__((address_space(3))) char*)(p))

// ---- helpers ----------------------------------------------------------------

// order-preserving float->uint encoding so unsigned atomicMin == float min
__device__ __forceinline__ unsigned enc_f32(float f) {
    unsigned u = __float_as_uint(f);
    return (u & 0x80000000u) ? ~u : (u | 0x80000000u);
}
__device__ __forceinline__ float dec_f32(unsigned u) {
    return (u & 0x80000000u) ? __uint_as_float(u & 0x7fffffffu)
                             : __uint_as_float(~u);
}
// fp32 -> bf16 bits, round-to-nearest-even
__device__ __forceinline__ short f2bf(float f) {
    unsigned u = __float_as_uint(f);
    u = u + 0x7fffu + ((u >> 16) & 1u);
    return (short)(u >> 16);
}

// Fragment-native global layout: element (row, k) with g16=row/16, r=row%16,
// kk=k/32, q=(k%32)/8, e=k%8 lives at  g16*2048 + kk*512 + q*128 + r*8 + e.
// One wave fragment load = base + lane*8 shorts = 64 lanes x 16 B contiguous.

// ---- kernel 1: prepass (coalesced via LDS transpose; verified R10/R11) ------
__global__ __launch_bounds__(256)
void prep_kernel(const float* __restrict__ z1, const float* __restrict__ z2,
                 short* __restrict__ z1b, short* __restrict__ z2b,
                 float* __restrict__ sq1, float* __restrict__ sq2,
                 float* __restrict__ posd, unsigned* __restrict__ rowmin,
                 unsigned* __restrict__ cnt, float* __restrict__ out) {
    __shared__ short l1[16 * 136], l2[16 * 136];    // 136 = 17*8: pad
    const int tid = threadIdx.x, b = blockIdx.x;
    const int r16 = tid >> 4, p = tid & 15;         // row-in-group, part
    const int row = b * 16 + r16;
    const int f0  = row * 32 + p * 2;               // 2 consecutive float4
    float4 fa0 = ((const float4*)z1)[f0], fa1 = ((const float4*)z1)[f0 + 1];
    float4 fb0 = ((const float4*)z2)[f0], fb1 = ((const float4*)z2)[f0 + 1];
    short8 sa = { f2bf(fa0.x), f2bf(fa0.y), f2bf(fa0.z), f2bf(fa0.w),
                  f2bf(fa1.x), f2bf(fa1.y), f2bf(fa1.z), f2bf(fa1.w) };
    short8 sb = { f2bf(fb0.x), f2bf(fb0.y), f2bf(fb0.z), f2bf(fb0.w),
                  f2bf(fb1.x), f2bf(fb1.y), f2bf(fb1.z), f2bf(fb1.w) };
    *(short8*)&l1[r16 * 136 + p * 8] = sa;
    *(short8*)&l2[r16 * 136 + p * 8] = sb;

    float s1 = fa0.x*fa0.x + fa0.y*fa0.y + fa0.z*fa0.z + fa0.w*fa0.w
             + fa1.x*fa1.x + fa1.y*fa1.y + fa1.z*fa1.z + fa1.w*fa1.w;
    float s2 = fb0.x*fb0.x + fb0.y*fb0.y + fb0.z*fb0.z + fb0.w*fb0.w
             + fb1.x*fb1.x + fb1.y*fb1.y + fb1.z*fb1.z + fb1.w*fb1.w;
    float dx0 = fa0.x-fb0.x, dy0 = fa0.y-fb0.y, dz0 = fa0.z-fb0.z, dw0 = fa0.w-fb0.w;
    float dx1 = fa1.x-fb1.x, dy1 = fa1.y-fb1.y, dz1 = fa1.z-fb1.z, dw1 = fa1.w-fb1.w;
    float p2 = dx0*dx0 + dy0*dy0 + dz0*dz0 + dw0*dw0
             + dx1*dx1 + dy1*dy1 + dz1*dz1 + dw1*dw1;
    #pragma unroll
    for (int m = 8; m >= 1; m >>= 1) {              // reduce over 16 parts
        s1 += __shfl_xor(s1, m);
        s2 += __shfl_xor(s2, m);
        p2 += __shfl_xor(p2, m);
    }
    if (p == 0) { sq1[row] = s1; sq2[row] = s2; posd[row] = sqrtf(p2); }

    __syncthreads();
    {   // out short8 #tid of this g16 block: r=tid&15, q=(tid>>4)&3, kk=(tid>>6)&3
        int r = tid & 15, psrc = ((tid >> 6) & 3) * 4 + ((tid >> 4) & 3);
        short8 va = *(const short8*)&l1[r * 136 + psrc * 8];
        short8 vb = *(const short8*)&l2[r * 136 + psrc * 8];
        *(short8*)&z1b[(size_t)b * 2048 + tid * 8] = va;   // 4 KB contiguous
        *(short8*)&z2b[(size_t)b * 2048 + tid * 8] = vb;
    }
    if (tid < 16) rowmin[b * 16 + tid] = 0xFFFFFFFFu;
    if (b == 0) {
        if (tid < 16) cnt[tid] = 0u;
        if (tid == 0) out[0] = 0.0f;
    }
}

// ---- kernel 2: B panel in LDS + PINNED A-fragment registers -----------------
// grid (64 panels x 16 rowgroups) = 1024 blocks = 4/CU. Panel staged once via
// global_load_lds, single barrier. The empty asm "+v" pins defeat the
// compiler's sink/remat heuristic (R9/R11: VGPR=52-56, frags re-loaded from
// global per iter); sched_barrier(0) per iter defeats the R10 batch-hoist of
// all ds_reads (290 MB scratch). Hand reg budget ~92 < 128 cap.
#define MFMA16(A, B, C) __builtin_amdgcn_mfma_f32_16x16x32_bf16((A), (B), (C), 0, 0, 0)

__global__ __launch_bounds__(256, 2)
void gemm_min_kernel(const short* __restrict__ z1b, const short* __restrict__ z2b,
                     const float* __restrict__ sq1, const float* __restrict__ sq2,
                     const float* __restrict__ posd,
                     unsigned* __restrict__ rowmin, unsigned* __restrict__ cnt,
                     float* __restrict__ out, int n)
{
    __shared__ short Bs[16384];                     // 32 KB B panel (128 cols)
    __shared__ float lsum[4];
    __shared__ int   fin_s;

    const int panel = blockIdx.x;                   // 128 cols
    const int rg    = blockIdx.y;                   // 512 rows
    const int tid = threadIdx.x, w = tid >> 6, lane = tid & 63;
    const int quad = lane >> 4, l15 = lane & 15;
    const int colp = panel * 128;

    const short* gB = z2b + (size_t)panel * 16384;
    #pragma unroll
    for (int it = 0; it < 8; ++it) {                // flat 32 KB DMA copy
        int off = it * 2048 + tid * 8;
        __builtin_amdgcn_global_load_lds(AS_GLOBAL(gB + off), AS_LDS(Bs + off), 16, 0, 0);
    }
    __syncthreads();                                // only barrier in the kernel

    // hoist sq2 for this panel: one value per ct per lane (static indices)
    float s2p[8];
    #pragma unroll
    for (int ct = 0; ct < 8; ++ct) s2p[ct] = sq2[colp + ct * 16 + l15];

    #pragma unroll 1
    for (int o = 0; o < 4; ++o) {
        const int rA = rg * 512 + w * 128 + o * 32; // two 16-row tiles
        const short* pa = z1b + (size_t)(rA >> 4) * 2048 + lane * 8;
        short8 a00 = *(const short8*)(pa +    0), a01 = *(const short8*)(pa +  512);
        short8 a02 = *(const short8*)(pa + 1024), a03 = *(const short8*)(pa + 1536);
        short8 a10 = *(const short8*)(pa + 2048), a11 = *(const short8*)(pa + 2560);
        short8 a12 = *(const short8*)(pa + 3072), a13 = *(const short8*)(pa + 3584);
        float vm0[4], vm1[4];
        #pragma unroll
        for (int r = 0; r < 4; ++r) { vm0[r] = 3.0e38f; vm1[r] = 3.0e38f; }

#define ITER(CT)                                                               \
    {                                                                          \
        asm volatile("" : "+v"(a00), "+v"(a01), "+v"(a02), "+v"(a03),          \
                          "+v"(a10), "+v"(a11), "+v"(a12), "+v"(a13),          \
                          "+v"(vm0[0]), "+v"(vm0[1]), "+v"(vm0[2]), "+v"(vm0[3]), \
                          "+v"(vm1[0]), "+v"(vm1[1]), "+v"(vm1[2]), "+v"(vm1[3]), \
                          "+v"(s2p[0]), "+v"(s2p[1]), "+v"(s2p[2]), "+v"(s2p[3]), \
                          "+v"(s2p[4]), "+v"(s2p[5]), "+v"(s2p[6]), "+v"(s2p[7])); \
        short8 bf0 = *(const short8*)&Bs[(CT) * 2048 +    0 + lane * 8];       \
        short8 bf1 = *(const short8*)&Bs[(CT) * 2048 +  512 + lane * 8];       \
        short8 bf2 = *(const short8*)&Bs[(CT) * 2048 + 1024 + lane * 8];       \
        short8 bf3 = *(const short8*)&Bs[(CT) * 2048 + 1536 + lane * 8];       \
        floatx4 c0 = (floatx4)0.0f, c1 = (floatx4)0.0f;                        \
        c0 = MFMA16(a00, bf0, c0);  c1 = MFMA16(a10, bf0, c1);                 \
        c0 = MFMA16(a01, bf1, c0);  c1 = MFMA16(a11, bf1, c1);                 \
        c0 = MFMA16(a02, bf2, c0);  c1 = MFMA16(a12, bf2, c1);                 \
        c0 = MFMA16(a03, bf3, c0);  c1 = MFMA16(a13, bf3, c1);                 \
        const int colb = colp + (CT) * 16;                                     \
        const float s2v = s2p[CT];                                             \
        const bool d0 = (colb == rA);                                          \
        const bool d1 = (colb == rA + 16);                                     \
        _Pragma("unroll")                                                      \
        for (int r = 0; r < 4; ++r) {                                          \
            bool eq = (quad * 4 + r) == l15;                                   \
            float v0 = fmaf(-2.0f, c0[r], s2v);                                \
            float v1 = fmaf(-2.0f, c1[r], s2v);                                \
            v0 = (d0 && eq) ? 3.0e38f : v0;                                    \
            v1 = (d1 && eq) ? 3.0e38f : v1;                                    \
            vm0[r] = fminf(vm0[r], v0);                                        \
            vm1[r] = fminf(vm1[r], v1);                                        \
        }                                                                      \
        __builtin_amdgcn_sched_barrier(0);                                     \
    }

        ITER(0) ITER(1) ITER(2) ITER(3) ITER(4) ITER(5) ITER(6) ITER(7)
#undef ITER

        // min over each quad's 16 lanes; one atomicMin per row
        #pragma unroll
        for (int r = 0; r < 4; ++r) {
            float v0 = vm0[r], v1 = vm1[r];
            #pragma unroll
            for (int m = 8; m >= 1; m >>= 1) {
                v0 = fminf(v0, __shfl_xor(v0, m));
                v1 = fminf(v1, __shfl_xor(v1, m));
            }
            if (l15 == 0) {
                atomicMin(&rowmin[rA + quad * 4 + r],      enc_f32(v0));
                atomicMin(&rowmin[rA + 16 + quad * 4 + r], enc_f32(v1));
            }
        }
    }

    __syncthreads();
    if (tid == 0) {
        __threadfence();    // release: this block's mins visible before bump
        fin_s = (atomicAdd(&cnt[rg], 1u) == 63u);
    }
    __syncthreads();
    if (!fin_s) return;
    __threadfence();        // acquire: see all 64 panels' mins

    // fused loss for rows [rg*512, rg*512+512): thread = two rows
    float acc = 0.0f;
    #pragma unroll
    for (int k = 0; k < 2; ++k) {
        int i = rg * 512 + k * 256 + tid;
        unsigned rm = atomicMin(&rowmin[i], 0xFFFFFFFFu);    // coherent forced read
        float hard = sqrtf(fmaxf(sq1[i] + dec_f32(rm), 0.0f));
        acc += fmaxf(posd[i] - hard + MARGIN, 0.0f);
    }
    #pragma unroll
    for (int m = 32; m >= 1; m >>= 1) acc += __shfl_xor(acc, m);
    if (lane == 0) lsum[w] = acc;
    __syncthreads();
    if (tid == 0)
        atomicAdd(out, (lsum[0] + lsum[1] + lsum[2] + lsum[3]) / (float)n);
}

// ---- launch -----------------------------------------------------------------
extern "C" void kernel_launch(void* const* d_in, const int* in_sizes, int n_in,
                              void* d_out, int out_size, void* d_ws, size_t ws_size,
                              hipStream_t stream) {
    const float* z1 = (const float*)d_in[0];
    const float* z2 = (const float*)d_in[1];
    const int n = in_sizes[0] / 128;            // 8192

    char* ws = (char*)d_ws;
    short*    z1b    = (short*)ws;                                     // 2 MB
    short*    z2b    = (short*)(ws + (size_t)n * 128 * 2);             // 2 MB
    float*    sq1    = (float*)(ws + (size_t)n * 128 * 4);             // 32 KB
    float*    sq2    = (float*)(ws + (size_t)n * 128 * 4 + n * 4);     // 32 KB
    float*    posd   = (float*)(ws + (size_t)n * 128 * 4 + n * 8);     // 32 KB
    unsigned* rowmin = (unsigned*)(ws + (size_t)n * 128 * 4 + n * 12); // 32 KB
    unsigned* cnt    = (unsigned*)(ws + (size_t)n * 128 * 4 + n * 16); // 64 B
    float*    out    = (float*)d_out;

    prep_kernel<<<n / 16, 256, 0, stream>>>(z1, z2, z1b, z2b, sq1, sq2, posd,
                                            rowmin, cnt, out);
    dim3 grid(64, n / 512);                     // (col panels, row groups)
    gemm_min_kernel<<<grid, 256, 0, stream>>>(z1b, z2b, sq1, sq2, posd,
                                              rowmin, cnt, out, n);
}